// Round 1
// baseline (158.277 us; speedup 1.0000x reference)
//
#include <hip/hip_runtime.h>
#include <stdint.h>

#define UNITS 4096
#define NBINS 256
#define HPAD  257   // padded stride so wave-private hist rows hit different banks

// one block (256 threads) per row; exact 4-pass MSB-first radix select of the
// KIDX-th smallest (ascending) element, then mask x >= theta.
__global__ __launch_bounds__(256) void ksparse_select_kernel(
        const float* __restrict__ X, float* __restrict__ out, int kidx) {
    __shared__ uint32_t su[UNITS];        // ordered-uint copy of the row (16 KiB)
    __shared__ uint32_t hist[4 * HPAD];   // per-wave 256-bin histograms (padded)
    __shared__ uint32_t wsum[4];
    __shared__ uint32_t sel[2];           // {selected bin, kk within bin}

    const int t    = threadIdx.x;
    const int w    = t >> 6;
    const int lane = t & 63;
    const size_t row = blockIdx.x;

    const float4* Xv = reinterpret_cast<const float4*>(X + row * UNITS);
    float4*       Ov = reinterpret_cast<float4*>(out + row * UNITS);
    uint4*       su4 = reinterpret_cast<uint4*>(su);

    // zero histograms (1028 words)
    for (int i = t; i < 4 * HPAD; i += 256) hist[i] = 0;

    // issue all global loads early
    float4 v[4];
#pragma unroll
    for (int j = 0; j < 4; ++j) v[j] = Xv[j * 256 + t];

    __syncthreads();  // hist zeroed before any atomics

    // convert to order-preserving uint, stash in LDS, build pass-0 histogram
#pragma unroll
    for (int j = 0; j < 4; ++j) {
        uint4 uu;
        uint32_t b;
        b = __float_as_uint(v[j].x); uu.x = (b & 0x80000000u) ? ~b : (b | 0x80000000u);
        b = __float_as_uint(v[j].y); uu.y = (b & 0x80000000u) ? ~b : (b | 0x80000000u);
        b = __float_as_uint(v[j].z); uu.z = (b & 0x80000000u) ? ~b : (b | 0x80000000u);
        b = __float_as_uint(v[j].w); uu.w = (b & 0x80000000u) ? ~b : (b | 0x80000000u);
        su4[j * 256 + t] = uu;
        atomicAdd(&hist[w * HPAD + (uu.x >> 24)], 1u);
        atomicAdd(&hist[w * HPAD + (uu.y >> 24)], 1u);
        atomicAdd(&hist[w * HPAD + (uu.z >> 24)], 1u);
        atomicAdd(&hist[w * HPAD + (uu.w >> 24)], 1u);
    }

    uint32_t kk = (uint32_t)kidx;
    uint32_t prefix = 0;

#pragma unroll 1
    for (int pass = 0; pass < 4; ++pass) {
        __syncthreads();  // histogram atomics done

        // reduce the 4 per-wave histograms; each thread owns one bin
        uint32_t tot = hist[0 * HPAD + t] + hist[1 * HPAD + t] +
                       hist[2 * HPAD + t] + hist[3 * HPAD + t];

        // wave-level inclusive scan over 64 lanes
        uint32_t incl = tot;
#pragma unroll
        for (int d = 1; d < 64; d <<= 1) {
            uint32_t x = __shfl_up(incl, d);
            if (lane >= d) incl += x;
        }
        if (lane == 63) wsum[w] = incl;
        __syncthreads();

        uint32_t off = 0;
#pragma unroll
        for (int ww = 0; ww < 4; ++ww) off += (ww < w) ? wsum[ww] : 0u;
        incl += off;
        uint32_t excl = incl - tot;
        if (kk >= excl && kk < incl) { sel[0] = (uint32_t)t; sel[1] = kk - excl; }
        __syncthreads();

        uint32_t bin = sel[0];
        kk = sel[1];
        prefix |= bin << (24 - 8 * pass);
        if (pass == 3) break;

        // zero hist for next digit
        for (int i = t; i < 4 * HPAD; i += 256) hist[i] = 0;
        __syncthreads();

        const int      shift = 16 - 8 * pass;                 // next digit
        const uint32_t pmask = 0xFFFFFFFFu << (24 - 8 * pass);  // decided bits
#pragma unroll
        for (int j = 0; j < 4; ++j) {
            uint4 uu = su4[j * 256 + t];
            uint32_t us0 = uu.x, us1 = uu.y, us2 = uu.z, us3 = uu.w;
            if ((us0 & pmask) == prefix) atomicAdd(&hist[w * HPAD + ((us0 >> shift) & 255u)], 1u);
            if ((us1 & pmask) == prefix) atomicAdd(&hist[w * HPAD + ((us1 >> shift) & 255u)], 1u);
            if ((us2 & pmask) == prefix) atomicAdd(&hist[w * HPAD + ((us2 >> shift) & 255u)], 1u);
            if ((us3 & pmask) == prefix) atomicAdd(&hist[w * HPAD + ((us3 >> shift) & 255u)], 1u);
        }
    }

    // prefix is the exact ordered-uint pattern of theta
    const uint32_t tu = prefix;
    const float theta = (tu & 0x80000000u) ? __uint_as_float(tu ^ 0x80000000u)
                                           : __uint_as_float(~tu);

    // masked write-back, recovering floats from the LDS copy
#pragma unroll
    for (int j = 0; j < 4; ++j) {
        uint4 uu = su4[j * 256 + t];
        float4 o;
        {
            uint32_t u = uu.x;
            float f = (u & 0x80000000u) ? __uint_as_float(u ^ 0x80000000u) : __uint_as_float(~u);
            o.x = (f >= theta) ? f : 0.0f;
        }
        {
            uint32_t u = uu.y;
            float f = (u & 0x80000000u) ? __uint_as_float(u ^ 0x80000000u) : __uint_as_float(~u);
            o.y = (f >= theta) ? f : 0.0f;
        }
        {
            uint32_t u = uu.z;
            float f = (u & 0x80000000u) ? __uint_as_float(u ^ 0x80000000u) : __uint_as_float(~u);
            o.z = (f >= theta) ? f : 0.0f;
        }
        {
            uint32_t u = uu.w;
            float f = (u & 0x80000000u) ? __uint_as_float(u ^ 0x80000000u) : __uint_as_float(~u);
            o.w = (f >= theta) ? f : 0.0f;
        }
        Ov[j * 256 + t] = o;
    }
}

extern "C" void kernel_launch(void* const* d_in, const int* in_sizes, int n_in,
                              void* d_out, int out_size, void* d_ws, size_t ws_size,
                              hipStream_t stream) {
    const float* X = (const float*)d_in[0];
    float* out = (float*)d_out;
    const int rows = in_sizes[0] / UNITS;
    const int kidx = (int)(0.7 * UNITS);  // 2867, matches reference's int(ZERO_RATIO*UNITS)
    ksparse_select_kernel<<<rows, 256, 0, stream>>>(X, out, kidx);
}

// Round 2
// 139.507 us; speedup vs baseline: 1.1345x; 1.1345x over previous
//
#include <hip/hip_runtime.h>
#include <stdint.h>

#define UNITS 4096
#define NB0 2048   // 11-bit digit bins

// One block (256 threads) per row. Row lives in registers (16 ordered-uint
// values per thread). Exact 3-pass MSB-first radix select (11/11/10 bits) of
// the kidx-th smallest, then masked write-back from registers.
__global__ __launch_bounds__(256, 8) void ksparse_select_kernel(
        const float* __restrict__ X, float* __restrict__ out, int kidx) {
    __shared__ uint32_t hist[NB0];   // 8 KiB, block-shared
    __shared__ uint32_t wsum[4];
    __shared__ uint32_t sel[2];      // {selected bin, rank within bin}

    const int t    = threadIdx.x;
    const int w    = t >> 6;
    const int lane = t & 63;
    const size_t row = blockIdx.x;

    const float4* Xv = reinterpret_cast<const float4*>(X + row * (size_t)UNITS);
    float4*       Ov = reinterpret_cast<float4*>(out + row * (size_t)UNITS);
    uint4*        h4 = reinterpret_cast<uint4*>(hist);

    // zero my 8 bins (thread t owns bins [8t, 8t+8))
    const uint4 z4 = make_uint4(0u, 0u, 0u, 0u);
    h4[2 * t]     = z4;
    h4[2 * t + 1] = z4;

    // load row into registers as order-preserving uints
    uint32_t uu[16];
#pragma unroll
    for (int j = 0; j < 4; ++j) {
        float4 v = Xv[j * 256 + t];
        uint32_t b;
        b = __float_as_uint(v.x); uu[4 * j + 0] = (b & 0x80000000u) ? ~b : (b | 0x80000000u);
        b = __float_as_uint(v.y); uu[4 * j + 1] = (b & 0x80000000u) ? ~b : (b | 0x80000000u);
        b = __float_as_uint(v.z); uu[4 * j + 2] = (b & 0x80000000u) ? ~b : (b | 0x80000000u);
        b = __float_as_uint(v.w); uu[4 * j + 3] = (b & 0x80000000u) ? ~b : (b | 0x80000000u);
    }

    __syncthreads();  // hist zeroed everywhere

    // pass-0 histogram: top 11 bits
#pragma unroll
    for (int e = 0; e < 16; ++e) atomicAdd(&hist[uu[e] >> 21], 1u);

    uint32_t kk   = (uint32_t)kidx;
    uint32_t pref = 0;

#pragma unroll 1
    for (int pass = 0; pass < 3; ++pass) {
        __syncthreads();  // histogram atomics done

        // read my 8 bins, then zero them (only owner touches them)
        uint4 a = h4[2 * t];
        uint4 b = h4[2 * t + 1];
        h4[2 * t]     = z4;
        h4[2 * t + 1] = z4;
        uint32_t h[8] = {a.x, a.y, a.z, a.w, b.x, b.y, b.z, b.w};
        uint32_t s = 0;
#pragma unroll
        for (int i = 0; i < 8; ++i) s += h[i];

        // wave inclusive scan of per-thread sums
        uint32_t incl = s;
#pragma unroll
        for (int d = 1; d < 64; d <<= 1) {
            uint32_t x = __shfl_up(incl, d);
            if (lane >= d) incl += x;
        }
        if (lane == 63) wsum[w] = incl;
        __syncthreads();

        uint32_t off = 0;
#pragma unroll
        for (int ww = 0; ww < 4; ++ww) off += (ww < w) ? wsum[ww] : 0u;
        incl += off;
        const uint32_t excl = incl - s;

        if (kk >= excl && kk < excl + s) {
            uint32_t c = excl, bin = 0, rem = 0;
#pragma unroll
            for (int i = 0; i < 8; ++i) {
                if (kk < c + h[i]) { bin = 8u * t + i; rem = kk - c; break; }
                c += h[i];
            }
            sel[0] = bin;
            sel[1] = rem;
        }
        __syncthreads();  // sel ready; also guarantees all bins re-zeroed

        const uint32_t bin = sel[0];
        kk = sel[1];

        if (pass == 0) {
            pref = bin;  // bits [31:21]
            // pass-1 histogram: bits [20:10] of elements matching the prefix
#pragma unroll
            for (int e = 0; e < 16; ++e)
                if ((uu[e] >> 21) == pref) atomicAdd(&hist[(uu[e] >> 10) & 2047u], 1u);
        } else if (pass == 1) {
            pref = (pref << 11) | bin;  // bits [31:10]
            // pass-2 histogram: bits [9:0]
#pragma unroll
            for (int e = 0; e < 16; ++e)
                if ((uu[e] >> 10) == pref) atomicAdd(&hist[uu[e] & 1023u], 1u);
        } else {
            pref = (pref << 10) | bin;  // full 32-bit pattern of theta
        }
    }

    const uint32_t tu = pref;
    const float theta_pos = __uint_as_float(tu ^ 0x80000000u);
    const float theta_neg = __uint_as_float(~tu);
    (void)theta_pos; (void)theta_neg;

    // masked write-back from registers; mask via ordered-uint compare
#pragma unroll
    for (int j = 0; j < 4; ++j) {
        float4 o;
#pragma unroll
        for (int c = 0; c < 4; ++c) {
            const uint32_t u = uu[4 * j + c];
            const float f = (u & 0x80000000u) ? __uint_as_float(u ^ 0x80000000u)
                                              : __uint_as_float(~u);
            const float r = (u >= tu) ? f : 0.0f;
            if (c == 0) o.x = r; else if (c == 1) o.y = r; else if (c == 2) o.z = r; else o.w = r;
        }
        Ov[j * 256 + t] = o;
    }
}

extern "C" void kernel_launch(void* const* d_in, const int* in_sizes, int n_in,
                              void* d_out, int out_size, void* d_ws, size_t ws_size,
                              hipStream_t stream) {
    const float* X = (const float*)d_in[0];
    float* out = (float*)d_out;
    const int rows = in_sizes[0] / UNITS;
    const int kidx = (int)(0.7 * UNITS);  // 2867
    ksparse_select_kernel<<<rows, 256, 0, stream>>>(X, out, kidx);
}